// Round 6
// baseline (474.977 us; speedup 1.0000x reference)
//
#include <hip/hip_runtime.h>
#include <stdint.h>

typedef __attribute__((ext_vector_type(8))) short s16x8;
typedef __attribute__((ext_vector_type(4))) float f32x4;

__device__ __forceinline__ short f2bf(float x) {
  uint32_t u = __builtin_bit_cast(uint32_t, x);
  u += 0x7FFFu + ((u >> 16) & 1u);  // RNE
  return (short)(u >> 16);
}

__device__ __forceinline__ void gload16(void* l, const void* g) {
  __builtin_amdgcn_global_load_lds(
      (const __attribute__((address_space(1))) void*)g,
      (__attribute__((address_space(3))) void*)l, 16, 0, 0);
}

__device__ __forceinline__ float gelu_tanh(float x) {
  float u = 0.7978845608028654f * (x + 0.044715f * x * x * x);
  float e = __expf(2.0f * u);
  return x - x / (e + 1.0f);
}

// Aq[m][:] = bf16(codebook[idx[m]][:])
__global__ void gather_cvt(const float* __restrict__ cb, const int* __restrict__ idx,
                           short* __restrict__ out) {
  int m = blockIdx.x * 2 + (threadIdx.x >> 7);
  int c = (threadIdx.x & 127) * 8;
  const float* s = cb + (size_t)idx[m] * 1024 + c;
  s16x8 o;
#pragma unroll
  for (int j = 0; j < 8; ++j) o[j] = f2bf(s[j]);
  *(s16x8*)(out + (size_t)m * 1024 + c) = o;
}

// in [K][N] fp32 -> out [N][K] bf16
__global__ void cvt_T(const float* __restrict__ in, short* __restrict__ out, int K, int N) {
  int Kb = K >> 3;
  int t = blockIdx.x * 256 + threadIdx.x;
  if (t >= N * Kb) return;
  int n = t / Kb;
  int k8 = (t - n * Kb) * 8;
  const float* s = in + (size_t)k8 * N + n;
  s16x8 o;
#pragma unroll
  for (int j = 0; j < 8; ++j) o[j] = f2bf(s[(size_t)j * N]);
  *(s16x8*)(out + (size_t)n * K + k8) = o;
}

// ---------------------------------------------------------------------------
// 2-phase 144x256x64 bf16 GEMM, 8 waves 1M x 8N (per-wave 144x32 = 9x2 frags,
// acc = 72 AGPR -> no register blowout, unlike BM=288's 144 AGPR).
// Grids are EXACT multiples of 256 CUs: GEMM1 2048 blocks (8 rounds, 100%),
// GEMM2 512 blocks (2 rounds, 100%).
// Per K-tile: 2 fat phases (16 / 20 MFMA), double-buffered LDS, counted vmcnt
// (4 then 2, never 0 in loop), XOR-swizzled LDS via pre-swizzled source +
// swizzled ds_read. A-tile = 2 full 64-row staging rounds + one 16-row round
// (waves 0-1 real, waves 2-7 -> 1KB LDS scratch to keep per-wave vmcnt
// uniform; scratch races are never read).
// MODE 1: epilogue bias+GELU -> bf16. MODE 2: epilogue bias -> fp32.
// ---------------------------------------------------------------------------
template <int MODE, int K, int N>
__global__ __launch_bounds__(512, 2) void gemm2p(
    const short* __restrict__ A, const short* __restrict__ Bt,
    const float* __restrict__ bias, void* __restrict__ Cv) {
  constexpr int BM = 144, BN = 256;
  constexpr int ATS = BM * 64;          // 9216 shorts
  constexpr int LDSH = (BM + BN) * 64;  // 25600 shorts
  __shared__ short lds[2 * LDSH + 512];  // + 1KB scratch = 103424 B

  constexpr int NBN = N / BN;
  const int nwg = gridDim.x;
  int swz = blockIdx.x;
  swz = (swz & 7) * (nwg >> 3) + (swz >> 3);  // XCD swizzle (nwg % 8 == 0)
  const int bm = swz / NBN, bn = swz - (swz / NBN) * NBN;  // row-major (A-panel L2 reuse)

  const int tid = threadIdx.x;
  const int wid = tid >> 6, lane = tid & 63;
  const int lr = lane & 15, hi = lane >> 4;

  // staging: round = 64 rows (8KB); thread -> row (tid>>3), phys slot tid&7,
  // source fetches logical slot (tid&7)^(row&7) (inverse swizzle on source)
  const int sl = (tid & 7) ^ ((tid >> 3) & 7);
  const long rstep = (long)64 * K;
  const short* aptr0 = A + (long)(bm * BM + (tid >> 3)) * K + sl * 8;
  const short* aptrP = A + (long)(bm * BM + 128 + ((tid >> 3) & 15)) * K + sl * 8;
  const short* bptr0 = Bt + (long)(bn * BN + (tid >> 3)) * K + sl * 8;
  const int wlds = wid * 512;  // wave's 1KB block within a round

  // ds_read bases; slot XOR-swizzled by row&7 (= lr&7: m/n-frag offsets are
  // multiples of 16 rows, so row&7 == lr&7)
  const int aRB = lr * 64;
  const int bRB = ATS + (wid * 32 + lr) * 64;
  const int sk0 = (hi ^ (lr & 7)) * 8;
  const int sk1 = ((4 + hi) ^ (lr & 7)) * 8;

  f32x4 acc[9][2] = {};
  s16x8 af[5][2], bf[2][2];

  constexpr int NT = K >> 6;

  // prologue: tile 0 -> buf0. Issue order: B0..B3, A0, A1, Ap.
#pragma unroll
  for (int r = 0; r < 4; ++r) gload16(&lds[ATS + r * 4096 + wlds], bptr0 + r * rstep);
  gload16(&lds[0 + wlds], aptr0);
  gload16(&lds[4096 + wlds], aptr0 + rstep);
  gload16((wid < 2) ? &lds[8192 + wlds] : &lds[2 * LDSH], aptrP);
  asm volatile("s_waitcnt vmcnt(2)" ::: "memory");  // B*,A0 landed; A1,Ap fly
  __builtin_amdgcn_s_barrier();

  for (int t = 0; t < NT; ++t) {
    const int cb = (t & 1) * LDSH;
    const int nb = LDSH - cb;
    const int kt = ((t + 1 < NT) ? (t + 1) : 0) << 6;

    // ---- phase 1: m-frags 0-3 (rows 0-63) x both n-frags; stage next B0-3 ----
#pragma unroll
    for (int mi = 0; mi < 4; ++mi) {
      af[mi][0] = *(const s16x8*)&lds[cb + aRB + mi * 1024 + sk0];
      af[mi][1] = *(const s16x8*)&lds[cb + aRB + mi * 1024 + sk1];
    }
#pragma unroll
    for (int nj = 0; nj < 2; ++nj) {
      bf[nj][0] = *(const s16x8*)&lds[cb + bRB + nj * 1024 + sk0];
      bf[nj][1] = *(const s16x8*)&lds[cb + bRB + nj * 1024 + sk1];
    }
#pragma unroll
    for (int r = 0; r < 4; ++r)
      gload16(&lds[nb + ATS + r * 4096 + wlds], bptr0 + r * rstep + kt);
    __builtin_amdgcn_s_barrier();
    asm volatile("s_waitcnt lgkmcnt(0)" ::: "memory");
    __builtin_amdgcn_s_setprio(1);
#pragma unroll
    for (int mi = 0; mi < 4; ++mi)
#pragma unroll
      for (int nj = 0; nj < 2; ++nj)
#pragma unroll
        for (int ks = 0; ks < 2; ++ks)
          acc[mi][nj] = __builtin_amdgcn_mfma_f32_16x16x32_bf16(af[mi][ks], bf[nj][ks], acc[mi][nj], 0, 0, 0);
    __builtin_amdgcn_s_setprio(0);
    asm volatile("s_waitcnt vmcnt(4)" ::: "memory");  // cur A1,Ap landed (for P2)
    __builtin_amdgcn_s_barrier();

    // ---- phase 2: m-frags 4-8 (rows 64-143) x both n-frags; stage next A0,A1,Ap ----
#pragma unroll
    for (int mi = 0; mi < 5; ++mi) {
      af[mi][0] = *(const s16x8*)&lds[cb + aRB + (4 + mi) * 1024 + sk0];
      af[mi][1] = *(const s16x8*)&lds[cb + aRB + (4 + mi) * 1024 + sk1];
    }
    gload16(&lds[nb + 0 + wlds], aptr0 + kt);
    gload16(&lds[nb + 4096 + wlds], aptr0 + rstep + kt);
    gload16((wid < 2) ? &lds[nb + 8192 + wlds] : &lds[2 * LDSH], aptrP + kt);
    __builtin_amdgcn_s_barrier();
    asm volatile("s_waitcnt lgkmcnt(0)" ::: "memory");
    __builtin_amdgcn_s_setprio(1);
#pragma unroll
    for (int mi = 0; mi < 5; ++mi)
#pragma unroll
      for (int nj = 0; nj < 2; ++nj)
#pragma unroll
        for (int ks = 0; ks < 2; ++ks)
          acc[4 + mi][nj] = __builtin_amdgcn_mfma_f32_16x16x32_bf16(af[mi][ks], bf[nj][ks], acc[4 + mi][nj], 0, 0, 0);
    __builtin_amdgcn_s_setprio(0);
    asm volatile("s_waitcnt vmcnt(2)" ::: "memory");  // next B0-3,A0 landed; A1,Ap fly
    __builtin_amdgcn_s_barrier();
  }

  // epilogue: C/D layout col=lane&15, row=(lane>>4)*4+r
  const int m0 = bm * BM + hi * 4;
  const int n0 = bn * BN + wid * 32 + lr;
#pragma unroll
  for (int nj = 0; nj < 2; ++nj) {
    const int n = n0 + nj * 16;
    const float bv = bias[n];
#pragma unroll
    for (int mi = 0; mi < 9; ++mi) {
      f32x4 v = acc[mi][nj];
#pragma unroll
      for (int r = 0; r < 4; ++r) {
        const int m = m0 + mi * 16 + r;
        float x = v[r] + bv;
        if (MODE == 1) {
          ((short*)Cv)[(size_t)m * N + n] = f2bf(gelu_tanh(x));
        } else {
          ((float*)Cv)[(size_t)m * N + n] = x;
        }
      }
    }
  }
}

extern "C" void kernel_launch(void* const* d_in, const int* in_sizes, int n_in,
                              void* d_out, int out_size, void* d_ws, size_t ws_size,
                              hipStream_t stream) {
  const int* idx = (const int*)d_in[0];
  const float* cb = (const float*)d_in[1];
  const float* W1 = (const float*)d_in[2];
  const float* b1 = (const float*)d_in[3];
  const float* W2 = (const float*)d_in[4];
  const float* b2 = (const float*)d_in[5];
  float* out = (float*)d_out;

  const int Mtot = 32 * 576;  // 18432 = 128 * 144

  // ws: Aq 40MB | W1T 8MB | W2T 8MB | h chunk
  char* ws = (char*)d_ws;
  short* aq = (short*)(ws);
  short* w1t = (short*)(ws + (size_t)40 * 1024 * 1024);
  short* w2t = (short*)(ws + (size_t)48 * 1024 * 1024);
  short* h = (short*)(ws + (size_t)56 * 1024 * 1024);

  gather_cvt<<<Mtot / 2, 256, 0, stream>>>(cb, idx, aq);
  cvt_T<<<2048, 256, 0, stream>>>(W1, w1t, 1024, 4096);  // -> [4096][1024]
  cvt_T<<<2048, 256, 0, stream>>>(W2, w2t, 4096, 1024);  // -> [1024][4096]

  size_t avail = (ws_size > (size_t)56 * 1024 * 1024) ? ws_size - (size_t)56 * 1024 * 1024 : 0;
  int nc = 1;
  while (nc < 8 && (size_t)(Mtot / nc) * 8192 > avail) nc <<= 1;
  const int Mc = Mtot / nc;  // Mc/144 = 128/nc, integer and %8==0 for nc in {1,2,4,8}

  for (int c = 0; c < nc; ++c) {
    gemm2p<1, 1024, 4096><<<(Mc / 144) * 16, 512, 0, stream>>>(
        aq + (size_t)c * Mc * 1024, w1t, b1, (void*)h);
    gemm2p<2, 4096, 1024><<<(Mc / 144) * 4, 512, 0, stream>>>(
        h, w2t, b2, (void*)(out + (size_t)c * Mc * 1024));
  }
}

// Round 7
// 419.615 us; speedup vs baseline: 1.1319x; 1.1319x over previous
//
#include <hip/hip_runtime.h>
#include <stdint.h>

typedef __attribute__((ext_vector_type(8))) short s16x8;
typedef __attribute__((ext_vector_type(4))) float f32x4;

__device__ __forceinline__ short f2bf(float x) {
  uint32_t u = __builtin_bit_cast(uint32_t, x);
  u += 0x7FFFu + ((u >> 16) & 1u);  // RNE
  return (short)(u >> 16);
}

__device__ __forceinline__ void gload16(void* l, const void* g) {
  __builtin_amdgcn_global_load_lds(
      (const __attribute__((address_space(1))) void*)g,
      (__attribute__((address_space(3))) void*)l, 16, 0, 0);
}

__device__ __forceinline__ float gelu_tanh(float x) {
  float u = 0.7978845608028654f * (x + 0.044715f * x * x * x);
  float e = __expf(2.0f * u);
  return x - x / (e + 1.0f);
}

// Aq[m][:] = bf16(codebook[idx[m]][:])
__global__ void gather_cvt(const float* __restrict__ cb, const int* __restrict__ idx,
                           short* __restrict__ out) {
  int m = blockIdx.x * 2 + (threadIdx.x >> 7);
  int c = (threadIdx.x & 127) * 8;
  const float* s = cb + (size_t)idx[m] * 1024 + c;
  s16x8 o;
#pragma unroll
  for (int j = 0; j < 8; ++j) o[j] = f2bf(s[j]);
  *(s16x8*)(out + (size_t)m * 1024 + c) = o;
}

// in [K][N] fp32 -> out [N][K] bf16
__global__ void cvt_T(const float* __restrict__ in, short* __restrict__ out, int K, int N) {
  int Kb = K >> 3;
  int t = blockIdx.x * 256 + threadIdx.x;
  if (t >= N * Kb) return;
  int n = t / Kb;
  int k8 = (t - n * Kb) * 8;
  const float* s = in + (size_t)k8 * N + n;
  s16x8 o;
#pragma unroll
  for (int j = 0; j < 8; ++j) o[j] = f2bf(s[(size_t)j * N]);
  *(s16x8*)(out + (size_t)n * K + k8) = o;
}

// ---------------------------------------------------------------------------
// Triple-buffered 144x256x64 bf16 GEMM, 8 waves 1M x 8N (per-wave 144x32 =
// 9x2 frags, acc = 72 AGPR; VGPR-cheap).
// LDS ring of 3 tile-buffers (154 KB): tile t reads ring[t%3], stages tile
// t+2 into ring[(t+2)%3]. End-of-tile wait = vmcnt(7) (exactly the 7 loads
// just issued) => tile t+1 proven landed; slack for each load ~2 tiles
// (~4 fat phases) which covers L3-hit latency. No WAR hazards in-tile =>
// ONE barrier per K-tile. 2 fat phases (16/20 MFMA), XOR-swizzled LDS via
// pre-swizzled source + swizzled ds_read, XCD-chunked row-major tiles.
// Grids are exact multiples of 256: GEMM1 2048 (8 rounds), GEMM2 512 (2).
// A-tile = 2 full 64-row staging rounds + 16-row partial (waves 0-1 real,
// waves 2-7 -> LDS scratch so per-wave vmcnt counts stay uniform).
// MODE 1: epilogue bias+GELU -> bf16. MODE 2: epilogue bias -> fp32.
// ---------------------------------------------------------------------------
template <int MODE, int K, int N>
__global__ __launch_bounds__(512, 2) void gemm3b(
    const short* __restrict__ A, const short* __restrict__ Bt,
    const float* __restrict__ bias, void* __restrict__ Cv) {
  constexpr int BM = 144, BN = 256;
  constexpr int ATS = BM * 64;          // 9216 shorts (A part of a buffer)
  constexpr int LDSH = (BM + BN) * 64;  // 25600 shorts per ring buffer
  __shared__ short lds[3 * LDSH + 512];  // 3 ring buffers + 1KB scratch = 154624 B

  constexpr int NBN = N / BN;
  const int nwg = gridDim.x;
  int swz = blockIdx.x;
  swz = (swz & 7) * (nwg >> 3) + (swz >> 3);  // XCD swizzle (nwg % 8 == 0)
  const int bm = swz / NBN, bn = swz - (swz / NBN) * NBN;  // row-major (A-panel L2 reuse)

  const int tid = threadIdx.x;
  const int wid = tid >> 6, lane = tid & 63;
  const int lr = lane & 15, hi = lane >> 4;

  // staging: round = 64 rows (8KB); thread -> row (tid>>3), phys slot tid&7,
  // source fetches logical slot (tid&7)^(row&7) (inverse swizzle on source)
  const int sl = (tid & 7) ^ ((tid >> 3) & 7);
  const long rstep = (long)64 * K;
  const short* aptr0 = A + (long)(bm * BM + (tid >> 3)) * K + sl * 8;
  const short* aptrP = A + (long)(bm * BM + 128 + ((tid >> 3) & 15)) * K + sl * 8;
  const short* bptr0 = Bt + (long)(bn * BN + (tid >> 3)) * K + sl * 8;
  const int wlds = wid * 512;            // wave's 1KB block within a round
  const bool realP = (wid < 2);
  constexpr int SCR = 3 * LDSH;          // scratch (partial-round dump, never read)

  // ds_read bases; slot XOR-swizzled by row&7 (= lr&7: frag row offsets are
  // multiples of 16)
  const int aRB = lr * 64;
  const int bRB = ATS + (wid * 32 + lr) * 64;
  const int sk0 = (hi ^ (lr & 7)) * 8;
  const int sk1 = ((4 + hi) ^ (lr & 7)) * 8;

  f32x4 acc[9][2] = {};
  s16x8 af[5][2], bf[2][2];

  constexpr int NT = K >> 6;

  // prologue: tiles 0,1 -> ring0, ring1 (7 loads each: B0-3, A0, A1, Ap)
#pragma unroll
  for (int tt = 0; tt < 2; ++tt) {
    const int wb = tt * LDSH, kk = tt * 64;
#pragma unroll
    for (int r = 0; r < 4; ++r) gload16(&lds[wb + ATS + r * 4096 + wlds], bptr0 + r * rstep + kk);
    gload16(&lds[wb + 0 + wlds], aptr0 + kk);
    gload16(&lds[wb + 4096 + wlds], aptr0 + rstep + kk);
    gload16(realP ? &lds[wb + 8192 + wlds] : &lds[SCR], aptrP + kk);
  }
  asm volatile("s_waitcnt vmcnt(7)" ::: "memory");  // tile0 landed; tile1 in flight
  __builtin_amdgcn_s_barrier();

  int rb0 = 0, rb1 = LDSH, rb2 = 2 * LDSH;  // read | next | write(t+2)

  for (int t = 0; t < NT; ++t) {
    const int kt = ((t + 2 < NT) ? (t + 2) : t) << 6;  // t+2 (wrap: reload cur, unused)

    // ---- phase 1: m-frags 0-3 x both n-frags; issue next-next B0-3 ----
#pragma unroll
    for (int mi = 0; mi < 4; ++mi) {
      af[mi][0] = *(const s16x8*)&lds[rb0 + aRB + mi * 1024 + sk0];
      af[mi][1] = *(const s16x8*)&lds[rb0 + aRB + mi * 1024 + sk1];
    }
#pragma unroll
    for (int nj = 0; nj < 2; ++nj) {
      bf[nj][0] = *(const s16x8*)&lds[rb0 + bRB + nj * 1024 + sk0];
      bf[nj][1] = *(const s16x8*)&lds[rb0 + bRB + nj * 1024 + sk1];
    }
#pragma unroll
    for (int r = 0; r < 4; ++r)
      gload16(&lds[rb2 + ATS + r * 4096 + wlds], bptr0 + r * rstep + kt);
    asm volatile("s_waitcnt lgkmcnt(0)" ::: "memory");
    __builtin_amdgcn_s_setprio(1);
#pragma unroll
    for (int mi = 0; mi < 4; ++mi)
#pragma unroll
      for (int nj = 0; nj < 2; ++nj)
#pragma unroll
        for (int ks = 0; ks < 2; ++ks)
          acc[mi][nj] = __builtin_amdgcn_mfma_f32_16x16x32_bf16(af[mi][ks], bf[nj][ks], acc[mi][nj], 0, 0, 0);
    __builtin_amdgcn_s_setprio(0);

    // ---- phase 2: m-frags 4-8 x both n-frags; issue next-next A0,A1,Ap ----
#pragma unroll
    for (int mi = 0; mi < 5; ++mi) {
      af[mi][0] = *(const s16x8*)&lds[rb0 + aRB + (4 + mi) * 1024 + sk0];
      af[mi][1] = *(const s16x8*)&lds[rb0 + aRB + (4 + mi) * 1024 + sk1];
    }
    gload16(&lds[rb2 + 0 + wlds], aptr0 + kt);
    gload16(&lds[rb2 + 4096 + wlds], aptr0 + rstep + kt);
    gload16(realP ? &lds[rb2 + 8192 + wlds] : &lds[SCR], aptrP + kt);
    asm volatile("s_waitcnt lgkmcnt(0)" ::: "memory");
    __builtin_amdgcn_s_setprio(1);
#pragma unroll
    for (int mi = 0; mi < 5; ++mi)
#pragma unroll
      for (int nj = 0; nj < 2; ++nj)
#pragma unroll
        for (int ks = 0; ks < 2; ++ks)
          acc[4 + mi][nj] = __builtin_amdgcn_mfma_f32_16x16x32_bf16(af[mi][ks], bf[nj][ks], acc[4 + mi][nj], 0, 0, 0);
    __builtin_amdgcn_s_setprio(0);

    // tile t+1 (7 loads issued during t-1) proven landed; only the 7 loads
    // issued this tile may remain in flight. One barrier per K-tile.
    asm volatile("s_waitcnt vmcnt(7)" ::: "memory");
    __builtin_amdgcn_s_barrier();
    const int tmp = rb0; rb0 = rb1; rb1 = rb2; rb2 = tmp;
  }

  // epilogue: C/D layout col=lane&15, row=(lane>>4)*4+r
  const int m0 = bm * BM + hi * 4;
  const int n0 = bn * BN + wid * 32 + lr;
#pragma unroll
  for (int nj = 0; nj < 2; ++nj) {
    const int n = n0 + nj * 16;
    const float bv = bias[n];
#pragma unroll
    for (int mi = 0; mi < 9; ++mi) {
      f32x4 v = acc[mi][nj];
#pragma unroll
      for (int r = 0; r < 4; ++r) {
        const int m = m0 + mi * 16 + r;
        float x = v[r] + bv;
        if (MODE == 1) {
          ((short*)Cv)[(size_t)m * N + n] = f2bf(gelu_tanh(x));
        } else {
          ((float*)Cv)[(size_t)m * N + n] = x;
        }
      }
    }
  }
}

extern "C" void kernel_launch(void* const* d_in, const int* in_sizes, int n_in,
                              void* d_out, int out_size, void* d_ws, size_t ws_size,
                              hipStream_t stream) {
  const int* idx = (const int*)d_in[0];
  const float* cb = (const float*)d_in[1];
  const float* W1 = (const float*)d_in[2];
  const float* b1 = (const float*)d_in[3];
  const float* W2 = (const float*)d_in[4];
  const float* b2 = (const float*)d_in[5];
  float* out = (float*)d_out;

  const int Mtot = 32 * 576;  // 18432 = 128 * 144

  // ws: Aq 40MB | W1T 8MB | W2T 8MB | h chunk
  char* ws = (char*)d_ws;
  short* aq = (short*)(ws);
  short* w1t = (short*)(ws + (size_t)40 * 1024 * 1024);
  short* w2t = (short*)(ws + (size_t)48 * 1024 * 1024);
  short* h = (short*)(ws + (size_t)56 * 1024 * 1024);

  gather_cvt<<<Mtot / 2, 256, 0, stream>>>(cb, idx, aq);
  cvt_T<<<2048, 256, 0, stream>>>(W1, w1t, 1024, 4096);  // -> [4096][1024]
  cvt_T<<<2048, 256, 0, stream>>>(W2, w2t, 4096, 1024);  // -> [1024][4096]

  size_t avail = (ws_size > (size_t)56 * 1024 * 1024) ? ws_size - (size_t)56 * 1024 * 1024 : 0;
  int nc = 1;
  while (nc < 8 && (size_t)(Mtot / nc) * 8192 > avail) nc <<= 1;
  const int Mc = Mtot / nc;  // Mc/144 = 128/nc, integer and %8==0 for nc in {1,2,4,8}

  for (int c = 0; c < nc; ++c) {
    gemm3b<1, 1024, 4096><<<(Mc / 144) * 16, 512, 0, stream>>>(
        aq + (size_t)c * Mc * 1024, w1t, b1, (void*)h);
    gemm3b<2, 4096, 1024><<<(Mc / 144) * 4, 512, 0, stream>>>(
        h, w2t, b2, (void*)(out + (size_t)c * Mc * 1024));
  }
}